// Round 8
// baseline (66.696 us; speedup 1.0000x reference)
//
#include <hip/hip_runtime.h>

// ACT-R activation recurrence — EDF schedule + SIMD-isolated serial chain.
// s_i = sum_{j<i} ((t_i-t_j)*H)^(-decay_j),  decay_j = w0 + w1*s_j  (s_0=0)
// (reference's max(diff*H,1) never binds: min gap 0.05 days * 2160 = 108)
// out[i-1,b] = sigmoid((ln(s_i)-TAU)/S), i=1..L-1.
//
// Identity: diff^(-decay_j) = exp2(q_ij*alpha_j), q_ij = -w1*log2(diff_ij),
// alpha = s + w0/w1; masked triangle entries q=-1e30 -> term 0.
//
// R8 hypothesis: waves map to SIMDs as (wv & 3). R5-R7 showed the phase time
// is dominated by the 64-step serial chain at ~90cyc/link (~3x its dependency
// latency) -> issue contention from waves 4/8/12 sharing SIMD0 with wave 0.
// Fix: waves 4, 8, 12 are IDLE (straight to barriers). Panels/build run on the
// 12 non-SIMD0 waves; strip on 8 of them. SIMD0 = wave 0 alone.

constexpr int   L  = 1024;
constexpr int   B  = 256;
constexpr int   T  = 64;
constexpr int   NT = 1024;   // 16 waves

constexpr float H_CONST = 86400.0f * 0.025f;   // 2160
constexpr float TAU_C   = -0.704205679427144f;
constexpr float S_C     = 0.254893976981164f;
constexpr float LN2     = 0.69314718055994530942f;
constexpr float LOG2E   = 1.4426950408889634074f;
constexpr float BIGNEG  = -1e30f;

typedef float f32x4 __attribute__((ext_vector_type(4)));

// EDF tile schedule: phases 1..14, tiles (r,c) with c <= r-2, window [c+1,r-1].
__device__ static const unsigned char TRr[105] = {
  2,3,4,5,6,7,8,9,
  3,4,5,6,7,8,9,
  4,5,6,7,8,9,10,10,
  5,6,7,8,9,10,10,11,
  6,7,8,9,10,11,11,11,
  7,8,9,10,11,11,12,12,
  8,9,10,11,12,12,12,13,
  9,10,11,12,12,12,13,13,
  10,11,12,13,13,13,13,14,
  11,12,13,13,13,14,14,14,
  12,13,14,14,14,14,15,15,
  13,14,14,14,14,15,15,15,
  14,15,15,15,15,15,15,15,
  15,15};
__device__ static const unsigned char TCc[105] = {
  0,0,0,0,0,0,0,0,
  1,1,1,1,1,1,1,
  2,2,2,2,2,2,0,1,
  3,3,3,3,3,2,3,0,
  4,4,4,4,4,1,2,3,
  5,5,5,5,4,5,0,1,
  6,6,6,6,2,3,4,0,
  7,7,7,5,6,7,1,2,
  8,8,8,3,4,5,6,0,
  9,9,7,8,9,1,2,3,
  10,10,4,5,6,7,0,1,
  11,8,9,10,11,2,3,4,
  12,5,6,7,8,9,10,11,
  12,13};
__device__ static const unsigned short POFF[17] =
  {0,0,8,15,23,31,39,47,55,63,71,79,87,95,103,105,105};

__device__ __forceinline__ float flog2(float x) { return __builtin_amdgcn_logf(x); }
__device__ __forceinline__ float fexp2(float x) { return __builtin_amdgcn_exp2f(x); }
__device__ __forceinline__ float rdlane(float v, int l) {
    return __uint_as_float(__builtin_amdgcn_readlane(__float_as_uint(v), l));
}

#define LOADCH(p0, p1, p2, p3, c)                                   \
    p0 = *(const f32x4*)(qb + 4 * ((4 * (c) + 0) ^ xk));            \
    p1 = *(const f32x4*)(qb + 4 * ((4 * (c) + 1) ^ xk));            \
    p2 = *(const f32x4*)(qb + 4 * ((4 * (c) + 2) ^ xk));            \
    p3 = *(const f32x4*)(qb + 4 * ((4 * (c) + 3) ^ xk));

#define KEEP4(a, b, c, d) \
    asm volatile("" : "+v"(a), "+v"(b), "+v"(c), "+v"(d));

#define RUN4(qv, J)                                                  \
    { float sg;                                                      \
      sg = rdlane(alpha, (J) + 0); alpha += fexp2(qv.x * sg);        \
      sg = rdlane(alpha, (J) + 1); alpha += fexp2(qv.y * sg);        \
      sg = rdlane(alpha, (J) + 2); alpha += fexp2(qv.z * sg);        \
      sg = rdlane(alpha, (J) + 3); alpha += fexp2(qv.w * sg); }

__global__ __launch_bounds__(NT)
void actr_kernel(const float* __restrict__ sp, const float* __restrict__ w,
                 float* __restrict__ out)
{
    __shared__ float  tH[L];
    __shared__ float  acc[L];       // partial sums from deferred tiles
    __shared__ float2 col[L];       // finalized columns {t_j, -decay_j}
    __shared__ float  qT[2][T * T]; // triangle q, swizzled row-major
    __shared__ float  stripsum[T];

    const int b    = blockIdx.x;
    const int tid  = threadIdx.x;
    const int lane = tid & 63;
    const int wv   = tid >> 6;
    const bool isIdle  = (wv != 0) && ((wv & 3) == 0);   // waves 4,8,12: SIMD0
    const bool isPanel = (wv != 0) && !isIdle;           // 12 worker waves
    // panel index 0..11 and strip index 0..7 (strip = panel waves 1..10 subset)
    const int pidx = (wv < 4) ? wv - 1 : (wv < 8) ? wv - 2 : (wv < 12) ? wv - 3
                                                                       : wv - 4;
    const float w0  = w[0];
    const float w1  = w[1];
    const float CSH = w0 / w1;

    for (int i = tid; i < L; i += NT) {
        tH[i]  = sp[i * B + b] * H_CONST;
        acc[i] = 0.0f;
    }
    if (tid < T) stripsum[tid] = 0.0f;
    __syncthreads();

    // prologue: build qT[0] for block 0
    for (int f = tid; f < T * T; f += NT) {
        const int j = f & 63, l2 = f >> 6;
        const float q = (j < l2) ? (-w1 * flog2(tH[l2] - tH[j])) : BIGNEG;
        qT[0][l2 * 64 + (j ^ (4 * (l2 & 15)))] = q;
    }
    __syncthreads();

    for (int k = 0; k < L / T; ++k) {
        const int I0 = k * T;
        const int xk = lane & 15;
        const float* qb = &qT[k & 1][lane * 64];

        f32x4 q0, q1, q2, q3, q4, q5, q6, q7, q8, q9, qa, qc, qd, qe, qf, qg;
        float acc_r = 0.0f;
        if (wv == 0) {
            // 64 q values -> 16 b128 loads, pinned across the barrier
            LOADCH(q0, q1, q2, q3, 0)
            LOADCH(q4, q5, q6, q7, 1)
            LOADCH(q8, q9, qa, qc, 2)
            LOADCH(qd, qe, qf, qg, 3)
            acc_r = acc[I0 + lane];
            KEEP4(q0, q1, q2, q3)
            KEEP4(q4, q5, q6, q7)
            KEEP4(q8, q9, qa, qc)
            KEEP4(qd, qe, qf, qg)
            asm volatile("" : "+v"(acc_r));
        }

        // strip: cols k-1 -> block-k rows; 8 worker waves, 8 threads/row
        if (k > 0 && isPanel && pidx < 8) {
            const int u  = pidx * 64 + lane;      // 0..511
            const int rl = u >> 3, c = u & 7;
            const float my_t = tH[I0 + rl];
            const float2* cb = &col[I0 - T];
            float p = 0.0f;
            #pragma unroll
            for (int uu = 0; uu < 8; ++uu) {
                const float2 cj = cb[c + 8 * uu];
                p += fexp2(cj.y * flog2(my_t - cj.x));
            }
            p += __shfl_xor(p, 1);
            p += __shfl_xor(p, 2);
            p += __shfl_xor(p, 4);
            if (c == 0) stripsum[rl] = p;
        }
        __syncthreads();

        if (wv == 0) {
            // serial triangle: pure-register chain, alone on SIMD0
            float alpha = acc_r + stripsum[lane] + CSH;
            __builtin_amdgcn_s_setprio(1);
            RUN4(q0,  0) RUN4(q1,  4) RUN4(q2,  8) RUN4(q3, 12)
            RUN4(q4, 16) RUN4(q5, 20) RUN4(q6, 24) RUN4(q7, 28)
            RUN4(q8, 32) RUN4(q9, 36) RUN4(qa, 40) RUN4(qc, 44)
            RUN4(qd, 48) RUN4(qe, 52) RUN4(qf, 56) RUN4(qg, 60)
            __builtin_amdgcn_s_setprio(0);
            const int r = I0 + lane;
            col[r] = make_float2(tH[r], -w1 * alpha);
            if (r > 0) {
                const float act = flog2(alpha - CSH) * LN2;   // ln(s_r)
                const float e   = fexp2((TAU_C - act) * (LOG2E / S_C));
                out[(r - 1) * B + b] = 1.0f / (1.0f + e);
            }
        } else if (isPanel) {
            // deferred tiles (EDF), quarter-tile units over 12 waves
            const int QT = 4 * (POFF[k + 1] - POFF[k]);
            const int wpe = (pidx + k) % 12;          // rotate straggler
            for (int h = wpe; h < QT; h += 12) {
                const int t     = POFF[k] + (h >> 2);
                const int rl    = 64 * (int)TRr[t] + 16 * (h & 3) + (lane >> 2);
                const int cbb   = 64 * (int)TCc[t];
                const float my_t = tH[rl];
                const float4* cp = reinterpret_cast<const float4*>(&col[cbb]);
                float a = 0.0f;
                #pragma unroll
                for (int u = 0; u < 8; ++u) {
                    const float4 c2 = cp[4 * u + (lane & 3)];
                    a += fexp2(c2.y * flog2(my_t - c2.x));
                    a += fexp2(c2.w * flog2(my_t - c2.z));
                }
                a += __shfl_xor(a, 1);
                a += __shfl_xor(a, 2);
                if ((lane & 3) == 0) atomicAdd(&acc[rl], a);
            }
            // build next block's triangle q (timestamps only)
            if (k < L / T - 1) {
                const int I1 = I0 + T;
                float* qn = &qT[(k + 1) & 1][0];
                const float vt = tH[I1 + lane];
                #pragma unroll
                for (int m = 0; m < 6; ++m) {
                    const int l2 = pidx + 12 * m;
                    if (l2 < 64) {
                        const float tl2 = rdlane(vt, l2);
                        const float q = (lane < l2) ? (-w1 * flog2(tl2 - vt))
                                                    : BIGNEG;
                        qn[l2 * 64 + (lane ^ (4 * (l2 & 15)))] = q;
                    }
                }
            }
        }
        // idle waves (4, 8, 12) fall straight through to the barrier
        __syncthreads();
    }
}

extern "C" void kernel_launch(void* const* d_in, const int* in_sizes, int n_in,
                              void* d_out, int out_size, void* d_ws, size_t ws_size,
                              hipStream_t stream) {
    const float* sp = (const float*)d_in[0];
    const float* w  = (const float*)d_in[1];
    float* out      = (float*)d_out;
    actr_kernel<<<dim3(B), dim3(NT), 0, stream>>>(sp, w, out);
}

// Round 9
// 45.801 us; speedup vs baseline: 1.4562x; 1.4562x over previous
//
#include <hip/hip_runtime.h>

// ACT-R activation recurrence — Chebyshev far-field compression.
// s_i = sum_{j<i} ((t_i-t_j)*H)^(-decay_j),  decay_j = w0 + w1*s_j  (s_0=0)
// (reference's max(diff*H,1) never binds: min gap 0.05 days * 2160 = 108)
// out[i-1,b] = sigmoid((ln(s_i)-TAU)/S), i=1..L-1.
//
// R9: R8's regression (fewer workers -> slower) proved the kernel is panel-
// work (transcendental-count) bound. Far tiles (r-c>=2) have their 64-col sum
// g(x) smooth over row-block r's time interval (nearest singularity |u|>2.5
// in Chebyshev coords -> 8-node fit rel-err ~3e-6). Per far tile: 8x64 exact
// node evals (8 pairs/lane) -> shfl reduce -> DCT (even/odd symmetric, const
// matrix) -> per-row Clenshaw (0 trans). Exact pairs: 524k -> ~150k.
// Strip (r-c=1, near-singular) and in-block triangle stay exact.

constexpr int   L  = 1024;
constexpr int   B  = 256;
constexpr int   T  = 64;
constexpr int   NT = 1024;   // 16 waves

constexpr float H_CONST = 86400.0f * 0.025f;   // 2160
constexpr float TAU_C   = -0.704205679427144f;
constexpr float S_C     = 0.254893976981164f;
constexpr float LN2     = 0.69314718055994530942f;
constexpr float LOG2E   = 1.4426950408889634074f;
constexpr float BIGNEG  = -1e30f;

// cos(k*pi/16)
constexpr float CC1 = 0.98078528040323044913f;
constexpr float CC2 = 0.92387953251128675613f;
constexpr float CC3 = 0.83146961230254523708f;
constexpr float CC4 = 0.70710678118654752440f;
constexpr float CC5 = 0.55557023301960222474f;
constexpr float CC6 = 0.38268343236508977173f;
constexpr float CC7 = 0.19509032201612826785f;

// Chebyshev nodes u_m = cos((2m+1)pi/16), m=0..7
__device__ static const float UNODE[8] =
  { CC1, CC3, CC5, CC7, -CC7, -CC5, -CC3, -CC1 };

typedef float f32x4 __attribute__((ext_vector_type(4)));

__device__ __forceinline__ float flog2(float x) { return __builtin_amdgcn_logf(x); }
__device__ __forceinline__ float fexp2(float x) { return __builtin_amdgcn_exp2f(x); }
__device__ __forceinline__ float rdlane(float v, int l) {
    return __uint_as_float(__builtin_amdgcn_readlane(__float_as_uint(v), l));
}

#define LOADCH(p0, p1, p2, p3, c)                                   \
    p0 = *(const f32x4*)(qb + 4 * ((4 * (c) + 0) ^ xk));            \
    p1 = *(const f32x4*)(qb + 4 * ((4 * (c) + 1) ^ xk));            \
    p2 = *(const f32x4*)(qb + 4 * ((4 * (c) + 2) ^ xk));            \
    p3 = *(const f32x4*)(qb + 4 * ((4 * (c) + 3) ^ xk));

#define KEEP4(a, b, c, d) \
    asm volatile("" : "+v"(a), "+v"(b), "+v"(c), "+v"(d));

#define RUN4(qv, J)                                                  \
    { float sg;                                                      \
      sg = rdlane(alpha, (J) + 0); alpha += fexp2(qv.x * sg);        \
      sg = rdlane(alpha, (J) + 1); alpha += fexp2(qv.y * sg);        \
      sg = rdlane(alpha, (J) + 2); alpha += fexp2(qv.z * sg);        \
      sg = rdlane(alpha, (J) + 3); alpha += fexp2(qv.w * sg); }

__global__ __launch_bounds__(NT)
void actr_kernel(const float* __restrict__ sp, const float* __restrict__ w,
                 float* __restrict__ out)
{
    __shared__ float  tH[L];
    __shared__ float  acc[L];       // far-field partial sums
    __shared__ float2 col[L];       // finalized columns {t_j, -decay_j}
    __shared__ float  qT[2][T * T]; // triangle q, swizzled row-major
    __shared__ float  stripsum[T];

    const int b    = blockIdx.x;
    const int tid  = threadIdx.x;
    const int lane = tid & 63;
    const int wv   = tid >> 6;
    const float w0  = w[0];
    const float w1  = w[1];
    const float CSH = w0 / w1;

    for (int i = tid; i < L; i += NT) {
        tH[i]  = sp[i * B + b] * H_CONST;
        acc[i] = 0.0f;
    }
    if (tid < T) stripsum[tid] = 0.0f;
    __syncthreads();

    // prologue: build qT[0] for block 0
    for (int f = tid; f < T * T; f += NT) {
        const int j = f & 63, l2 = f >> 6;
        const float q = (j < l2) ? (-w1 * flog2(tH[l2] - tH[j])) : BIGNEG;
        qT[0][l2 * 64 + (j ^ (4 * (l2 & 15)))] = q;
    }
    __syncthreads();

    for (int k = 0; k < L / T; ++k) {
        const int I0 = k * T;
        const int xk = lane & 15;
        const float* qb = &qT[k & 1][lane * 64];

        f32x4 q0, q1, q2, q3, q4, q5, q6, q7, q8, q9, qa, qc, qd, qe, qf, qg;
        float acc_r = 0.0f;
        if (wv == 0) {
            // 64 q values -> 16 b128 loads, pinned across the barrier
            LOADCH(q0, q1, q2, q3, 0)
            LOADCH(q4, q5, q6, q7, 1)
            LOADCH(q8, q9, qa, qc, 2)
            LOADCH(qd, qe, qf, qg, 3)
            acc_r = acc[I0 + lane];
            KEEP4(q0, q1, q2, q3)
            KEEP4(q4, q5, q6, q7)
            KEEP4(q8, q9, qa, qc)
            KEEP4(qd, qe, qf, qg)
            asm volatile("" : "+v"(acc_r));
        }

        // strip: cols k-1 -> block-k rows (exact; r-c=1 can be near-singular)
        if (k > 0) {
            const int rl = tid >> 4, c = tid & 15;
            const float my_t = tH[I0 + rl];
            const float2* cb = &col[I0 - T];
            float p = 0.0f;
            #pragma unroll
            for (int uu = 0; uu < 4; ++uu) {
                const float2 cj = cb[c + 16 * uu];
                p += fexp2(cj.y * flog2(my_t - cj.x));
            }
            p += __shfl_xor(p, 1);
            p += __shfl_xor(p, 2);
            p += __shfl_xor(p, 4);
            p += __shfl_xor(p, 8);
            if (c == 0) stripsum[rl] = p;
        }
        __syncthreads();

        if (wv == 0) {
            // serial triangle: pure-register chain
            float alpha = acc_r + stripsum[lane] + CSH;
            __builtin_amdgcn_s_setprio(1);
            RUN4(q0,  0) RUN4(q1,  4) RUN4(q2,  8) RUN4(q3, 12)
            RUN4(q4, 16) RUN4(q5, 20) RUN4(q6, 24) RUN4(q7, 28)
            RUN4(q8, 32) RUN4(q9, 36) RUN4(qa, 40) RUN4(qc, 44)
            RUN4(qd, 48) RUN4(qe, 52) RUN4(qf, 56) RUN4(qg, 60)
            __builtin_amdgcn_s_setprio(0);
            const int r = I0 + lane;
            col[r] = make_float2(tH[r], -w1 * alpha);
            if (r > 0) {
                const float act = flog2(alpha - CSH) * LN2;   // ln(s_r)
                const float e   = fexp2((TAU_C - act) * (LOG2E / S_C));
                out[(r - 1) * B + b] = 1.0f / (1.0f + e);
            }
        } else {
            // far tile (r, k-1), r = k + wv, via Chebyshev-8 (k>=1, wv<=15-k)
            if (k >= 1 && wv <= 15 - k) {
                const int r  = k + wv;
                const int m  = lane >> 3;       // node index
                const int g  = lane & 7;        // col group
                const float At  = tH[r * 64];
                const float Bt  = tH[r * 64 + 63];
                const float mid = 0.5f * (At + Bt);
                const float hf  = 0.5f * (Bt - At);
                const float xm  = fmaf(hf, UNODE[m], mid);
                // exact evals at node xm over 8 columns
                const float2* cb = &col[(k - 1) * 64 + g * 8];
                float gm = 0.0f;
                #pragma unroll
                for (int jj = 0; jj < 8; ++jj) {
                    const float2 cj = cb[jj];
                    gm += fexp2(cj.y * flog2(xm - cj.x));
                }
                gm += __shfl_xor(gm, 1);
                gm += __shfl_xor(gm, 2);
                gm += __shfl_xor(gm, 4);    // group m holds g_m
                const float g0 = rdlane(gm,  0), g1 = rdlane(gm,  8);
                const float g2 = rdlane(gm, 16), g3 = rdlane(gm, 24);
                const float g4 = rdlane(gm, 32), g5 = rdlane(gm, 40);
                const float g6 = rdlane(gm, 48), g7 = rdlane(gm, 56);
                // DCT -> Chebyshev coefficients (even/odd symmetry)
                const float s0 = g0 + g7, s1 = g1 + g6, s2 = g2 + g5, s3 = g3 + g4;
                const float d0 = g0 - g7, d1 = g1 - g6, d2 = g2 - g5, d3 = g3 - g4;
                const float a0 = 0.125f * (s0 + s1 + s2 + s3);
                const float a2 = 0.25f * (CC2 * (s0 - s3) + CC6 * (s1 - s2));
                const float a4 = 0.25f * CC4 * (s0 - s1 - s2 + s3);
                const float a6 = 0.25f * (CC6 * (s0 - s3) - CC2 * (s1 - s2));
                const float a1 = 0.25f * (CC1*d0 + CC3*d1 + CC5*d2 + CC7*d3);
                const float a3 = 0.25f * (CC3*d0 - CC7*d1 - CC1*d2 - CC5*d3);
                const float a5 = 0.25f * (CC5*d0 - CC1*d1 + CC7*d2 + CC3*d3);
                const float a7 = 0.25f * (CC7*d0 - CC5*d1 + CC3*d2 - CC1*d3);
                // per-row Clenshaw (row = lane)
                const int   i  = r * 64 + lane;
                const float u  = (tH[i] - mid) * __builtin_amdgcn_rcpf(hf);
                const float u2 = u + u;
                float bk1 = a7;
                float bk  = fmaf(u2, a7, a6);
                float tt;
                tt = fmaf(u2, bk, a5) - bk1; bk1 = bk; bk = tt;
                tt = fmaf(u2, bk, a4) - bk1; bk1 = bk; bk = tt;
                tt = fmaf(u2, bk, a3) - bk1; bk1 = bk; bk = tt;
                tt = fmaf(u2, bk, a2) - bk1; bk1 = bk; bk = tt;
                tt = fmaf(u2, bk, a1) - bk1; bk1 = bk; bk = tt;
                const float p = fmaf(u, bk, a0) - bk1;
                acc[i] += p;    // unique rows per wave per phase: no atomics
            }
            // build next block's triangle q (timestamps only), 15 waves
            if (k < L / T - 1) {
                const int I1 = I0 + T;
                float* qn = &qT[(k + 1) & 1][0];
                const float vt = tH[I1 + lane];
                #pragma unroll
                for (int m2 = 0; m2 < 5; ++m2) {
                    const int l2 = (wv - 1) + 15 * m2;
                    if (l2 < 64) {
                        const float tl2 = rdlane(vt, l2);
                        const float q = (lane < l2) ? (-w1 * flog2(tl2 - vt))
                                                    : BIGNEG;
                        qn[l2 * 64 + (lane ^ (4 * (l2 & 15)))] = q;
                    }
                }
            }
        }
        __syncthreads();
    }
}

extern "C" void kernel_launch(void* const* d_in, const int* in_sizes, int n_in,
                              void* d_out, int out_size, void* d_ws, size_t ws_size,
                              hipStream_t stream) {
    const float* sp = (const float*)d_in[0];
    const float* w  = (const float*)d_in[1];
    float* out      = (float*)d_out;
    actr_kernel<<<dim3(B), dim3(NT), 0, stream>>>(sp, w, out);
}